// Round 6
// baseline (903.238 us; speedup 1.0000x reference)
//
#include <hip/hip_runtime.h>
#include <math.h>

#define HW 65536
#define NC 10
#define NT 12
#define LAMBDA_F 0.05f
#define PI_F 3.14159265358979323846f
// XOR-swizzle for wave-private LDS fft scratch
#define SWZ(i) ((i) ^ ((i) >> 4))

__device__ __forceinline__ float2 cadd(float2 a, float2 b){ return make_float2(a.x+b.x, a.y+b.y); }
__device__ __forceinline__ float2 csub(float2 a, float2 b){ return make_float2(a.x-b.x, a.y-b.y); }
__device__ __forceinline__ float2 cmul(float2 a, float2 b){ return make_float2(a.x*b.x-a.y*b.y, a.x*b.y+a.y*b.x); }
// conj(a)*b
__device__ __forceinline__ float2 cmulj(float2 a, float2 b){ return make_float2(a.x*b.x+a.y*b.y, a.x*b.y-a.y*b.x); }
__device__ __forceinline__ float2 cscale(float2 a, float s){ return make_float2(a.x*s, a.y*s); }

template<int SIGN>
__device__ __forceinline__ void radix4_nt(float2& a0, float2& a1, float2& a2, float2& a3){
  float2 t0=cadd(a0,a2), t1=csub(a0,a2), t2=cadd(a1,a3), t3=csub(a1,a3);
  float2 t3r;
  if constexpr (SIGN < 0) t3r = make_float2(t3.y, -t3.x); else t3r = make_float2(-t3.y, t3.x);
  a0=cadd(t0,t2); a1=cadd(t1,t3r); a2=csub(t0,t2); a3=csub(t1,t3r);
}

// w = exp(-2*pi*i*e/256) held in registers; conj applied for SIGN=+1.
template<int SIGN>
__device__ __forceinline__ void radix4_tw(float2& a0, float2& a1, float2& a2, float2& a3, float2 w){
  if constexpr (SIGN > 0) w.y = -w.y;
  float2 w2 = cmul(w, w);
  float2 w3 = cmul(w, w2);
  a1 = cmul(a1, w); a2 = cmul(a2, w2); a3 = cmul(a3, w3);
  radix4_nt<SIGN>(a0, a1, a2, a3);
}

__device__ __forceinline__ float2 twf(int e){
  float s, c;
  __sincosf(-2.0f*PI_F*(float)e*(1.0f/256.0f), &s, &c);
  return make_float2(c, s);
}

// 256-pt Stockham radix-4 FFT, natural order in/out, unnormalized.
// SINGLE wave-private scratch buffer b (256 float2): each stage's ds_write is
// register-dependent on the prior ds_read, and per-wave LDS ops execute in
// order, so write-after-read on the same buffer is safe (relied on since r2).
template<int SIGN>
__device__ __forceinline__ void fft256(float2* b, int j,
                                       float2 wA, float2 wB, float2 wC,
                                       float2& x0, float2& x1, float2& x2, float2& x3){
  radix4_nt<SIGN>(x0,x1,x2,x3);
  b[SWZ(4*j)]=x0; b[SWZ(4*j+1)]=x1; b[SWZ(4*j+2)]=x2; b[SWZ(4*j+3)]=x3;
  x0=b[SWZ(j)]; x1=b[SWZ(j+64)]; x2=b[SWZ(j+128)]; x3=b[SWZ(j+192)];
  radix4_tw<SIGN>(x0,x1,x2,x3, wA);
  { int i=((j>>2)<<4)+(j&3); b[SWZ(i)]=x0; b[SWZ(i+4)]=x1; b[SWZ(i+8)]=x2; b[SWZ(i+12)]=x3; }
  x0=b[SWZ(j)]; x1=b[SWZ(j+64)]; x2=b[SWZ(j+128)]; x3=b[SWZ(j+192)];
  radix4_tw<SIGN>(x0,x1,x2,x3, wB);
  { int i=((j>>4)<<6)+(j&15); b[SWZ(i)]=x0; b[SWZ(i+16)]=x1; b[SWZ(i+32)]=x2; b[SWZ(i+48)]=x3; }
  x0=b[SWZ(j)]; x1=b[SWZ(j+64)]; x2=b[SWZ(j+128)]; x3=b[SWZ(j+192)];
  radix4_tw<SIGN>(x0,x1,x2,x3, wC);
}

// Reconstruct alpha_{it-1}, beta_{it-1} from reduced scalars (verified r3/r5).
// scal: [0]=rs0 ; per k: [8+8k]=pAp.re [+1]=pAp.im [+2]=rAp.re [+3]=rAp.im [+4]=|Ap|^2
__device__ __forceinline__ void cg_scalars(const float* __restrict__ scal, int it,
                                           float& a_re, float& a_im, float& beta){
  float rs = scal[0]; a_re = 0.f; a_im = 0.f; beta = 0.f;
  for (int k = 0; k < it; k++){
    float pr = scal[8+8*k+0], pi = scal[8+8*k+1];
    float rr_ = scal[8+8*k+2], ri_ = scal[8+8*k+3];
    float aa = scal[8+8*k+4];
    float den = pr*pr + pi*pi;
    a_re =  rs*pr/den;
    a_im = -rs*pi/den;
    float re_ = a_re*rr_ - a_im*ri_;   // Re(alpha * rAp)
    float rs_next = rs - 2.0f*re_ + (a_re*a_re + a_im*a_im)*aa;
    beta = rs_next/rs;
    rs = rs_next;
  }
}

// ---------- S0: W9 precompute + g = D*sum_t conj(L) y (into bufB) + scal zero
__global__ __launch_bounds__(256) void k_setup(const float* __restrict__ mask,
                                               const float2* __restrict__ Lt,
                                               const float2* __restrict__ y,
                                               float* __restrict__ W9,
                                               float2* __restrict__ bufB,
                                               float* __restrict__ scal){
  int tid = threadIdx.x;
  int u = blockIdx.x;
  if (u == 0 && tid < 128) scal[tid] = 0.0f;
  if (u < 256){
    int kx = u, ky = tid;
    int mx = (kx + 128) & 255, my = (ky + 128) & 255;
    float d0=0.f,d1=0.f,d2=0.f;
    float2 o01=make_float2(0,0), o02=make_float2(0,0), o12=make_float2(0,0);
    for (int t = 0; t < NT; t++){
      float m = mask[t*HW + my*256 + mx];
      float2 l0 = Lt[t*3+0], l1 = Lt[t*3+1], l2 = Lt[t*3+2];
      d0 += m*(l0.x*l0.x + l0.y*l0.y);
      d1 += m*(l1.x*l1.x + l1.y*l1.y);
      d2 += m*(l2.x*l2.x + l2.y*l2.y);
      o01 = cadd(o01, cscale(cmulj(l0,l1), m));
      o02 = cadd(o02, cscale(cmulj(l0,l2), m));
      o12 = cadd(o12, cscale(cmulj(l1,l2), m));
    }
    const float nrm = 1.0f/65536.0f;
    int idx = kx*256 + ky;
    W9[idx]      = d0*nrm;  W9[idx+HW]   = d1*nrm;  W9[idx+2*HW] = d2*nrm;
    W9[idx+3*HW] = o01.x*nrm; W9[idx+4*HW] = o01.y*nrm;
    W9[idx+5*HW] = o02.x*nrm; W9[idx+6*HW] = o02.y*nrm;
    W9[idx+7*HW] = o12.x*nrm; W9[idx+8*HW] = o12.y*nrm;
  } else {
    int idx = (u-256)*256 + tid;
    int c = idx >> 16, pix = idx & (HW-1);
    int xx = pix & 255, yy2 = pix >> 8;
    float sg = ((xx + yy2) & 1) ? -1.0f : 1.0f;
    float2 a0=make_float2(0,0), a1=make_float2(0,0), a2=make_float2(0,0);
    for (int t = 0; t < NT; t++){
      float2 yv = y[((size_t)(t*NC + c))*HW + pix];
      a0 = cadd(a0, cmulj(Lt[t*3+0], yv));
      a1 = cadd(a1, cmulj(Lt[t*3+1], yv));
      a2 = cadd(a2, cmulj(Lt[t*3+2], yv));
    }
    bufB[((size_t)(c*3+0))*HW + pix] = cscale(a0, sg);
    bufB[((size_t)(c*3+1))*HW + pix] = cscale(a1, sg);
    bufB[((size_t)(c*3+2))*HW + pix] = cscale(a2, sg);
  }
}

// ---------- setup row IFFT (-1): bufB row-major -> bufA transposed [pl][kx][y]
// 512 threads = 8 waves, 1 row each; tile row doubles as fft scratch.
__global__ __launch_bounds__(512) void k_rows_plain(const float2* __restrict__ src,
                                                    float2* __restrict__ dst){
  __shared__ float2 tile[8][256];
  int tid = threadIdx.x, g = tid >> 6, j = tid & 63;
  float2 wA = twf((j&3)<<4), wB = twf((j&15)<<2), wC = twf(j);
  int pl = blockIdx.y, ri = blockIdx.x;
  int row = ri*8 + g;
  const float2* sr = src + (size_t)pl*HW + row*256;
  float2 x0=sr[j], x1=sr[j+64], x2=sr[j+128], x3=sr[j+192];
  fft256<-1>(tile[g], j, wA,wB,wC, x0,x1,x2,x3);
  tile[g][j]=x0; tile[g][j+64]=x1; tile[g][j+128]=x2; tile[g][j+192]=x3;
  __syncthreads();
  float2* dT = dst + (size_t)pl*HW;
  int yo2 = (tid&3)*2, kxo = tid>>2;
  #pragma unroll
  for (int kb = 0; kb < 2; kb++){
    int kx = kb*128 + kxo;
    float2 a = tile[yo2][kx], b = tile[yo2+1][kx];
    *(float4*)(dT + (size_t)kx*256 + ri*8 + yo2) = make_float4(a.x,a.y,b.x,b.y);
  }
}

// ---------- setup col IFFT (-1): bufA [pl][kx][y] contiguous -> bufB row-major
// 512 threads = 8 waves, 1 column each.
__global__ __launch_bounds__(512) void k_cols_plain(const float2* __restrict__ src,
                                                    float2* __restrict__ dst){
  __shared__ float2 tile[8][256];
  int tid = threadIdx.x, g = tid >> 6, j = tid & 63;
  float2 wA = twf((j&3)<<4), wB = twf((j&15)<<2), wC = twf(j);
  int pl = blockIdx.y, kg = blockIdx.x;
  int kx = kg*8 + g;
  const float2* col = src + (size_t)pl*HW + (size_t)kx*256;
  float2 x0=col[j], x1=col[j+64], x2=col[j+128], x3=col[j+192];
  fft256<-1>(tile[g], j, wA,wB,wC, x0,x1,x2,x3);
  tile[g][j]=x0; tile[g][j+64]=x1; tile[g][j+128]=x2; tile[g][j+192]=x3;
  __syncthreads();
  float2* d = dst + (size_t)pl*HW;
  int kxo2 = (tid&3)*2, yy = tid>>2;
  #pragma unroll
  for (int yb = 0; yb < 2; yb++){
    int yc = yb*128 + yy;
    float2 a = tile[kxo2][yc], b = tile[kxo2+1][yc];
    *(float4*)(d + (size_t)yc*256 + kg*8 + kxo2) = make_float4(a.x,a.y,b.x,b.y);
  }
}

// ---------- b = D * sum_c conj(S_c) * bufB + lambda*mo ; p=r=b ; z=0 ; rs0
__global__ __launch_bounds__(256) void k_compute_b(const float2* __restrict__ A,
                                                   const float2* __restrict__ sens,
                                                   const float2* __restrict__ mo,
                                                   float2* __restrict__ p,
                                                   float2* __restrict__ r,
                                                   float2* __restrict__ z,
                                                   float* __restrict__ scal){
  __shared__ float red[4];
  int idx = blockIdx.x*256 + threadIdx.x;
  int s = idx >> 16, pix = idx & (HW-1);
  int xx = pix & 255, yy = pix >> 8;
  float sg = ((xx + yy) & 1) ? -1.0f : 1.0f;
  float2 accv = make_float2(0,0);
  for (int c = 0; c < NC; c++)
    accv = cadd(accv, cmulj(sens[(size_t)c*HW + pix], A[((size_t)(c*3+s))*HW + pix]));
  float2 b = cadd(cscale(accv, sg), cscale(mo[idx], LAMBDA_F));
  p[idx] = b; r[idx] = b; z[idx] = make_float2(0,0);
  float part = b.x*b.x + b.y*b.y;
  for (int off = 32; off; off >>= 1) part += __shfl_down(part, off);
  int j = threadIdx.x & 63, w = threadIdx.x >> 6;
  if (j == 0) red[w] = part;
  __syncthreads();
  if (threadIdx.x == 0) atomicAdd(&scal[0], red[0]+red[1]+red[2]+red[3]);
}

// ---------- A: fused CG update (z,r,p) + sens-mult + row FFT (+1) -> bufA (T)
// 512 threads = 8 waves, 1 row each.
__global__ __launch_bounds__(512) void k_rows_op(const float2* __restrict__ rprev,
                                                 const float2* __restrict__ pprev,
                                                 const float2* __restrict__ Apb,
                                                 float2* __restrict__ pout,
                                                 float2* __restrict__ rout,
                                                 float2* __restrict__ z,
                                                 const float2* __restrict__ sens,
                                                 float2* __restrict__ dst,
                                                 const float* __restrict__ scal, int iter){
  __shared__ float2 tile[8][256];
  int tid = threadIdx.x, g = tid >> 6, j = tid & 63;
  float2 wA = twf((j&3)<<4), wB = twf((j&15)<<2), wC = twf(j);
  int pl = blockIdx.y, ri = blockIdx.x;
  int c = pl/3, sp = pl - 3*c;
  int row = ri*8 + g;
  int base = row*256;
  const float2* Sp = sens + (size_t)c*HW;
  float a_re=0.f, a_im=0.f, beta=0.f;
  if (iter > 0) cg_scalars(scal, iter, a_re, a_im, beta);
  size_t pb = (size_t)sp*HW + base;
  float2 pv[4];
  if (iter == 0){
    pv[0]=pprev[pb+j]; pv[1]=pprev[pb+j+64]; pv[2]=pprev[pb+j+128]; pv[3]=pprev[pb+j+192];
  } else {
    #pragma unroll
    for (int q = 0; q < 4; q++){
      int x = j + 64*q;
      float2 pe = pprev[pb+x], re_ = rprev[pb+x], ae = Apb[pb+x];
      float2 rnew = make_float2(re_.x - (a_re*ae.x - a_im*ae.y),
                                re_.y - (a_re*ae.y + a_im*ae.x));
      pv[q] = make_float2(rnew.x + beta*pe.x, rnew.y + beta*pe.y);
      if (c == 0){
        rout[pb+x] = rnew;
        pout[pb+x] = pv[q];
        float2 ze = z[pb+x];
        z[pb+x] = make_float2(ze.x + a_re*pe.x - a_im*pe.y,
                              ze.y + a_re*pe.y + a_im*pe.x);
      }
    }
  }
  float2 x0 = cmul(Sp[base+j],     pv[0]);
  float2 x1 = cmul(Sp[base+j+64],  pv[1]);
  float2 x2 = cmul(Sp[base+j+128], pv[2]);
  float2 x3 = cmul(Sp[base+j+192], pv[3]);
  fft256<1>(tile[g], j, wA,wB,wC, x0,x1,x2,x3);
  tile[g][j]=x0; tile[g][j+64]=x1; tile[g][j+128]=x2; tile[g][j+192]=x3;
  __syncthreads();
  float2* dT = dst + (size_t)pl*HW;
  int yo2 = (tid&3)*2, kxo = tid>>2;
  #pragma unroll
  for (int kb = 0; kb < 2; kb++){
    int kx = kb*128 + kxo;
    float2 a = tile[yo2][kx], b = tile[yo2+1][kx];
    *(float4*)(dT + (size_t)kx*256 + ri*8 + yo2) = make_float4(a.x,a.y,b.x,b.y);
  }
}

// ---------- B: col FFT(+1) -> 3x3 W -> col IFFT(-1); bufA contiguous -> bufB row-major
// 384 threads = 6 waves: wave w -> (s = w>>1, kxl = w&1); 2 kx per block.
__global__ __launch_bounds__(384) void k_cols_W(const float2* __restrict__ src,
                                                float2* __restrict__ dst,
                                                const float* __restrict__ W9){
  __shared__ float2 tile[6][256];
  int tid = threadIdx.x, w = tid >> 6, j = tid & 63;
  float2 wA = twf((j&3)<<4), wB = twf((j&15)<<2), wC = twf(j);
  int kg = blockIdx.x, c = blockIdx.y;
  int s = w >> 1, kxl = w & 1;
  int kx = kg*2 + kxl;
  // forward col FFT (contiguous read)
  {
    const float2* col = src + ((size_t)(c*3+s))*HW + (size_t)kx*256;
    float2 x0=col[j], x1=col[j+64], x2=col[j+128], x3=col[j+192];
    fft256<1>(tile[w], j, wA,wB,wC, x0,x1,x2,x3);
    tile[w][j]=x0; tile[w][j+64]=x1; tile[w][j+128]=x2; tile[w][j+192]=x3;
  }
  __syncthreads();
  // W combine: this wave produces U_s at its kx, reading all 3 s' planes
  float2 U[4];
  #pragma unroll
  for (int q = 0; q < 4; q++){
    int k = j + 64*q;
    int wi = kx*256 + k;
    float2 v0 = tile[0*2+kxl][k], v1 = tile[1*2+kxl][k], v2 = tile[2*2+kxl][k];
    if (s == 0){
      float d0 = W9[wi];
      float2 o01 = make_float2(W9[wi+3*HW], W9[wi+4*HW]);
      float2 o02 = make_float2(W9[wi+5*HW], W9[wi+6*HW]);
      U[q] = cadd(cadd(cscale(v0,d0), cmul(o01,v1)), cmul(o02,v2));
    } else if (s == 1){
      float d1 = W9[wi+HW];
      float2 o01 = make_float2(W9[wi+3*HW], W9[wi+4*HW]);
      float2 o12 = make_float2(W9[wi+7*HW], W9[wi+8*HW]);
      U[q] = cadd(cadd(cmulj(o01,v0), cscale(v1,d1)), cmul(o12,v2));
    } else {
      float d2 = W9[wi+2*HW];
      float2 o02 = make_float2(W9[wi+5*HW], W9[wi+6*HW]);
      float2 o12 = make_float2(W9[wi+7*HW], W9[wi+8*HW]);
      U[q] = cadd(cadd(cmulj(o02,v0), cmulj(o12,v1)), cscale(v2,d2));
    }
  }
  __syncthreads();   // all combine reads done before tile reused as scratch
  {
    float2 x0=U[0], x1=U[1], x2=U[2], x3=U[3];
    fft256<-1>(tile[w], j, wA,wB,wC, x0,x1,x2,x3);
    tile[w][j]=x0; tile[w][j+64]=x1; tile[w][j+128]=x2; tile[w][j+192]=x3;
  }
  __syncthreads();
  // transposed write row-major: float4 covers kx pair (kg*2, kg*2+1)
  int s_out = tid >> 7, yy = tid & 127;
  #pragma unroll
  for (int yb = 0; yb < 2; yb++){
    int yc = yb*128 + yy;
    float2 a = tile[s_out*2+0][yc], b = tile[s_out*2+1][yc];
    float2* d = dst + ((size_t)(c*3+s_out))*HW;
    *(float4*)(d + (size_t)yc*256 + kg*2) = make_float4(a.x,a.y,b.x,b.y);
  }
}

// ---------- C: row IFFT(-1) + conj(S) combine + lambda*p -> Ap; reduce pAp,rAp,|Ap|^2
// 640 threads = 10 waves, wave w -> coil c=w, 1 FFT each; scratch doubles as acc.
__global__ __launch_bounds__(640) void k_rows_acc(const float2* __restrict__ Bp,
                                                  const float2* __restrict__ sens,
                                                  const float2* __restrict__ p,
                                                  const float2* __restrict__ r,
                                                  float2* __restrict__ Ap,
                                                  float* __restrict__ scal, int iter){
  __shared__ float2 scratch[10][256];
  __shared__ float red5[4][5];
  int tid = threadIdx.x, w = tid >> 6, j = tid & 63;
  float2 wA = twf((j&3)<<4), wB = twf((j&15)<<2), wC = twf(j);
  int row = blockIdx.x, s = blockIdx.y;
  {
    int c = w;
    const float2* src = Bp + ((size_t)(c*3+s))*HW + row*256;
    float2 x0=src[j], x1=src[j+64], x2=src[j+128], x3=src[j+192];
    fft256<-1>(scratch[w], j, wA,wB,wC, x0,x1,x2,x3);
    const float2* Sc = sens + (size_t)c*HW + row*256;
    scratch[w][j]     = cmulj(Sc[j],     x0);
    scratch[w][j+64]  = cmulj(Sc[j+64],  x1);
    scratch[w][j+128] = cmulj(Sc[j+128], x2);
    scratch[w][j+192] = cmulj(Sc[j+192], x3);
  }
  __syncthreads();
  if (tid < 256){
    int k = tid;
    float2 a = make_float2(0,0);
    #pragma unroll
    for (int c = 0; c < NC; c++) a = cadd(a, scratch[c][k]);
    size_t ob = (size_t)s*HW + row*256 + k;
    float2 pv = p[ob];
    float2 ap = cadd(a, cscale(pv, LAMBDA_F));
    Ap[ob] = ap;
    float2 rv = r[ob];
    float s0 = pv.x*ap.x + pv.y*ap.y;   // pAp.re
    float s1 = pv.x*ap.y - pv.y*ap.x;   // pAp.im
    float s2 = rv.x*ap.x + rv.y*ap.y;   // rAp.re
    float s3 = rv.x*ap.y - rv.y*ap.x;   // rAp.im
    float s4 = ap.x*ap.x + ap.y*ap.y;   // |Ap|^2
    for (int off = 32; off; off >>= 1){
      s0 += __shfl_down(s0, off); s1 += __shfl_down(s1, off);
      s2 += __shfl_down(s2, off); s3 += __shfl_down(s3, off);
      s4 += __shfl_down(s4, off);
    }
    if (j == 0){ red5[w][0]=s0; red5[w][1]=s1; red5[w][2]=s2; red5[w][3]=s3; red5[w][4]=s4; }
  }
  __syncthreads();
  if (tid == 0){
    atomicAdd(&scal[8+8*iter+0], red5[0][0]+red5[1][0]+red5[2][0]+red5[3][0]);
    atomicAdd(&scal[8+8*iter+1], red5[0][1]+red5[1][1]+red5[2][1]+red5[3][1]);
    atomicAdd(&scal[8+8*iter+2], red5[0][2]+red5[1][2]+red5[2][2]+red5[3][2]);
    atomicAdd(&scal[8+8*iter+3], red5[0][3]+red5[1][3]+red5[2][3]+red5[3][3]);
    atomicAdd(&scal[8+8*iter+4], red5[0][4]+red5[1][4]+red5[2][4]+red5[3][4]);
  }
}

// ---------- final: z += alpha_9 * p_9
__global__ __launch_bounds__(256) void k_zfin(float2* __restrict__ z,
                                              const float2* __restrict__ p9,
                                              const float* __restrict__ scal){
  float a_re, a_im, beta;
  cg_scalars(scal, 10, a_re, a_im, beta);
  int idx = blockIdx.x*256 + threadIdx.x;
  float2 pe = p9[idx], ze = z[idx];
  z[idx] = make_float2(ze.x + a_re*pe.x - a_im*pe.y,
                       ze.y + a_re*pe.y + a_im*pe.x);
}

extern "C" void kernel_launch(void* const* d_in, const int* in_sizes, int n_in,
                              void* d_out, int out_size, void* d_ws, size_t ws_size,
                              hipStream_t stream){
  const float2* y    = (const float2*)d_in[0];
  const float2* mo   = (const float2*)d_in[1];
  const float2* sens = (const float2*)d_in[2];
  const float2* Lt   = (const float2*)d_in[3];
  const float*  mask = (const float*)d_in[4];

  float* w = (float*)d_ws;
  float*  scal = w;                                  // 128 floats
  float*  W9   = w + 128;                            // 9*HW floats
  float2* bufA = (float2*)(w + 128 + 9*HW);          // 30 planes (transposed k-space)
  float2* bufB = bufA + (size_t)30*HW;               // 30 planes (row-major)
  float2* p0   = bufB + (size_t)30*HW;
  float2* p1   = p0 + (size_t)3*HW;
  float2* r0   = p1 + (size_t)3*HW;
  float2* r1   = r0 + (size_t)3*HW;
  float2* Ap   = r1 + (size_t)3*HW;
  float2* z    = (float2*)d_out;

  // setup
  k_setup<<<2816, 256, 0, stream>>>(mask, Lt, y, W9, bufB, scal);
  k_rows_plain<<<dim3(32, 30), 512, 0, stream>>>(bufB, bufA);
  k_cols_plain<<<dim3(32, 30), 512, 0, stream>>>(bufA, bufB);
  k_compute_b<<<768, 256, 0, stream>>>(bufB, sens, mo, p0, r0, z, scal);

  // CG iterations: 3 kernels each (update fused into rows_op)
  for (int it = 0; it < 10; it++){
    float2* pprev = (it == 0) ? p0 : ((it & 1) ? p0 : p1);
    float2* rprev = (it == 0) ? r0 : ((it & 1) ? r0 : r1);
    float2* pw = (it & 1) ? p1 : p0;   // p_it
    float2* rw = (it & 1) ? r1 : r0;   // r_it
    k_rows_op<<<dim3(32, 30), 512, 0, stream>>>(rprev, pprev, Ap, pw, rw, z, sens, bufA, scal, it);
    k_cols_W<<<dim3(128, 10), 384, 0, stream>>>(bufA, bufB, W9);
    k_rows_acc<<<dim3(256, 3), 640, 0, stream>>>(bufB, sens, pw, rw, Ap, scal, it);
  }
  k_zfin<<<768, 256, 0, stream>>>(z, p1, scal);
}

// Round 7
// 475.619 us; speedup vs baseline: 1.8991x; 1.8991x over previous
//
#include <hip/hip_runtime.h>
#include <math.h>

#define HW 65536
#define NC 10
#define NT 12
#define LAMBDA_F 0.05f
#define PI_F 3.14159265358979323846f
// XOR-swizzle for wave-private LDS fft scratch
#define SWZ(i) ((i) ^ ((i) >> 4))

__device__ __forceinline__ float2 cadd(float2 a, float2 b){ return make_float2(a.x+b.x, a.y+b.y); }
__device__ __forceinline__ float2 csub(float2 a, float2 b){ return make_float2(a.x-b.x, a.y-b.y); }
__device__ __forceinline__ float2 cmul(float2 a, float2 b){ return make_float2(a.x*b.x-a.y*b.y, a.x*b.y+a.y*b.x); }
// conj(a)*b
__device__ __forceinline__ float2 cmulj(float2 a, float2 b){ return make_float2(a.x*b.x+a.y*b.y, a.x*b.y-a.y*b.x); }
__device__ __forceinline__ float2 cscale(float2 a, float s){ return make_float2(a.x*s, a.y*s); }

template<int SIGN>
__device__ __forceinline__ void radix4_nt(float2& a0, float2& a1, float2& a2, float2& a3){
  float2 t0=cadd(a0,a2), t1=csub(a0,a2), t2=cadd(a1,a3), t3=csub(a1,a3);
  float2 t3r;
  if constexpr (SIGN < 0) t3r = make_float2(t3.y, -t3.x); else t3r = make_float2(-t3.y, t3.x);
  a0=cadd(t0,t2); a1=cadd(t1,t3r); a2=csub(t0,t2); a3=csub(t1,t3r);
}

// w = exp(-2*pi*i*e/256) held in registers; conj applied for SIGN=+1.
template<int SIGN>
__device__ __forceinline__ void radix4_tw(float2& a0, float2& a1, float2& a2, float2& a3, float2 w){
  if constexpr (SIGN > 0) w.y = -w.y;
  float2 w2 = cmul(w, w);
  float2 w3 = cmul(w, w2);
  a1 = cmul(a1, w); a2 = cmul(a2, w2); a3 = cmul(a3, w3);
  radix4_nt<SIGN>(a0, a1, a2, a3);
}

__device__ __forceinline__ float2 twf(int e){
  float s, c;
  __sincosf(-2.0f*PI_F*(float)e*(1.0f/256.0f), &s, &c);
  return make_float2(c, s);
}

// 256-pt Stockham radix-4 FFT, natural order in/out, unnormalized.
// Single wave-private scratch buffer b (256 float2); per-wave LDS ops are
// in-order so write-after-read on the same buffer is safe (relied on since r2).
template<int SIGN>
__device__ __forceinline__ void fft256(float2* b, int j,
                                       float2 wA, float2 wB, float2 wC,
                                       float2& x0, float2& x1, float2& x2, float2& x3){
  radix4_nt<SIGN>(x0,x1,x2,x3);
  b[SWZ(4*j)]=x0; b[SWZ(4*j+1)]=x1; b[SWZ(4*j+2)]=x2; b[SWZ(4*j+3)]=x3;
  x0=b[SWZ(j)]; x1=b[SWZ(j+64)]; x2=b[SWZ(j+128)]; x3=b[SWZ(j+192)];
  radix4_tw<SIGN>(x0,x1,x2,x3, wA);
  { int i=((j>>2)<<4)+(j&3); b[SWZ(i)]=x0; b[SWZ(i+4)]=x1; b[SWZ(i+8)]=x2; b[SWZ(i+12)]=x3; }
  x0=b[SWZ(j)]; x1=b[SWZ(j+64)]; x2=b[SWZ(j+128)]; x3=b[SWZ(j+192)];
  radix4_tw<SIGN>(x0,x1,x2,x3, wB);
  { int i=((j>>4)<<6)+(j&15); b[SWZ(i)]=x0; b[SWZ(i+16)]=x1; b[SWZ(i+32)]=x2; b[SWZ(i+48)]=x3; }
  x0=b[SWZ(j)]; x1=b[SWZ(j+64)]; x2=b[SWZ(j+128)]; x3=b[SWZ(j+192)];
  radix4_tw<SIGN>(x0,x1,x2,x3, wC);
}

// Reconstruct alpha_{it-1}, beta_{it-1} from reduced scalars (verified r3/r5).
// scal: [0]=rs0 ; per k: [8+8k]=pAp.re [+1]=pAp.im [+2]=rAp.re [+3]=rAp.im [+4]=|Ap|^2
__device__ __forceinline__ void cg_scalars(const float* __restrict__ scal, int it,
                                           float& a_re, float& a_im, float& beta){
  float rs = scal[0]; a_re = 0.f; a_im = 0.f; beta = 0.f;
  for (int k = 0; k < it; k++){
    float pr = scal[8+8*k+0], pi = scal[8+8*k+1];
    float rr_ = scal[8+8*k+2], ri_ = scal[8+8*k+3];
    float aa = scal[8+8*k+4];
    float den = pr*pr + pi*pi;
    a_re =  rs*pr/den;
    a_im = -rs*pi/den;
    float re_ = a_re*rr_ - a_im*ri_;   // Re(alpha * rAp)
    float rs_next = rs - 2.0f*re_ + (a_re*a_re + a_im*a_im)*aa;
    beta = rs_next/rs;
    rs = rs_next;
  }
}

// ---------- S0: W9 precompute + g = D*sum_t conj(L) y (into bufB)
__global__ __launch_bounds__(256) void k_setup(const float* __restrict__ mask,
                                               const float2* __restrict__ Lt,
                                               const float2* __restrict__ y,
                                               float* __restrict__ W9,
                                               float2* __restrict__ bufB){
  int tid = threadIdx.x;
  int u = blockIdx.x;
  if (u < 256){
    int kx = u, ky = tid;
    int mx = (kx + 128) & 255, my = (ky + 128) & 255;
    float d0=0.f,d1=0.f,d2=0.f;
    float2 o01=make_float2(0,0), o02=make_float2(0,0), o12=make_float2(0,0);
    for (int t = 0; t < NT; t++){
      float m = mask[t*HW + my*256 + mx];
      float2 l0 = Lt[t*3+0], l1 = Lt[t*3+1], l2 = Lt[t*3+2];
      d0 += m*(l0.x*l0.x + l0.y*l0.y);
      d1 += m*(l1.x*l1.x + l1.y*l1.y);
      d2 += m*(l2.x*l2.x + l2.y*l2.y);
      o01 = cadd(o01, cscale(cmulj(l0,l1), m));
      o02 = cadd(o02, cscale(cmulj(l0,l2), m));
      o12 = cadd(o12, cscale(cmulj(l1,l2), m));
    }
    const float nrm = 1.0f/65536.0f;
    int idx = kx*256 + ky;
    W9[idx]      = d0*nrm;  W9[idx+HW]   = d1*nrm;  W9[idx+2*HW] = d2*nrm;
    W9[idx+3*HW] = o01.x*nrm; W9[idx+4*HW] = o01.y*nrm;
    W9[idx+5*HW] = o02.x*nrm; W9[idx+6*HW] = o02.y*nrm;
    W9[idx+7*HW] = o12.x*nrm; W9[idx+8*HW] = o12.y*nrm;
  } else {
    int idx = (u-256)*256 + tid;
    int c = idx >> 16, pix = idx & (HW-1);
    int xx = pix & 255, yy2 = pix >> 8;
    float sg = ((xx + yy2) & 1) ? -1.0f : 1.0f;
    float2 a0=make_float2(0,0), a1=make_float2(0,0), a2=make_float2(0,0);
    for (int t = 0; t < NT; t++){
      float2 yv = y[((size_t)(t*NC + c))*HW + pix];
      a0 = cadd(a0, cmulj(Lt[t*3+0], yv));
      a1 = cadd(a1, cmulj(Lt[t*3+1], yv));
      a2 = cadd(a2, cmulj(Lt[t*3+2], yv));
    }
    bufB[((size_t)(c*3+0))*HW + pix] = cscale(a0, sg);
    bufB[((size_t)(c*3+1))*HW + pix] = cscale(a1, sg);
    bufB[((size_t)(c*3+2))*HW + pix] = cscale(a2, sg);
  }
}

// ---------- setup row IFFT (-1): bufB row-major -> bufA transposed [pl][kx][y]
__global__ __launch_bounds__(512) void k_rows_plain(const float2* __restrict__ src,
                                                    float2* __restrict__ dst){
  __shared__ float2 tile[8][256];
  int tid = threadIdx.x, g = tid >> 6, j = tid & 63;
  float2 wA = twf((j&3)<<4), wB = twf((j&15)<<2), wC = twf(j);
  int pl = blockIdx.y, ri = blockIdx.x;
  int row = ri*8 + g;
  const float2* sr = src + (size_t)pl*HW + row*256;
  float2 x0=sr[j], x1=sr[j+64], x2=sr[j+128], x3=sr[j+192];
  fft256<-1>(tile[g], j, wA,wB,wC, x0,x1,x2,x3);
  tile[g][j]=x0; tile[g][j+64]=x1; tile[g][j+128]=x2; tile[g][j+192]=x3;
  __syncthreads();
  float2* dT = dst + (size_t)pl*HW;
  int yo2 = (tid&3)*2, kxo = tid>>2;
  #pragma unroll
  for (int kb = 0; kb < 2; kb++){
    int kx = kb*128 + kxo;
    float2 a = tile[yo2][kx], b = tile[yo2+1][kx];
    *(float4*)(dT + (size_t)kx*256 + ri*8 + yo2) = make_float4(a.x,a.y,b.x,b.y);
  }
}

// ---------- setup col IFFT (-1): bufA [pl][kx][y] contiguous -> bufB row-major
__global__ __launch_bounds__(512) void k_cols_plain(const float2* __restrict__ src,
                                                    float2* __restrict__ dst){
  __shared__ float2 tile[8][256];
  int tid = threadIdx.x, g = tid >> 6, j = tid & 63;
  float2 wA = twf((j&3)<<4), wB = twf((j&15)<<2), wC = twf(j);
  int pl = blockIdx.y, kg = blockIdx.x;
  int kx = kg*8 + g;
  const float2* col = src + (size_t)pl*HW + (size_t)kx*256;
  float2 x0=col[j], x1=col[j+64], x2=col[j+128], x3=col[j+192];
  fft256<-1>(tile[g], j, wA,wB,wC, x0,x1,x2,x3);
  tile[g][j]=x0; tile[g][j+64]=x1; tile[g][j+128]=x2; tile[g][j+192]=x3;
  __syncthreads();
  float2* d = dst + (size_t)pl*HW;
  int kxo2 = (tid&3)*2, yy = tid>>2;
  #pragma unroll
  for (int yb = 0; yb < 2; yb++){
    int yc = yb*128 + yy;
    float2 a = tile[kxo2][yc], b = tile[kxo2+1][yc];
    *(float4*)(d + (size_t)yc*256 + kg*8 + kxo2) = make_float4(a.x,a.y,b.x,b.y);
  }
}

// ---------- b = D * sum_c conj(S_c) * bufB + lambda*mo ; p=r=b ; z=0 ; rs0 partial
__global__ __launch_bounds__(256) void k_compute_b(const float2* __restrict__ A,
                                                   const float2* __restrict__ sens,
                                                   const float2* __restrict__ mo,
                                                   float2* __restrict__ p,
                                                   float2* __restrict__ r,
                                                   float2* __restrict__ z,
                                                   float* __restrict__ part){
  __shared__ float red[4];
  int idx = blockIdx.x*256 + threadIdx.x;
  int s = idx >> 16, pix = idx & (HW-1);
  int xx = pix & 255, yy = pix >> 8;
  float sg = ((xx + yy) & 1) ? -1.0f : 1.0f;
  float2 accv = make_float2(0,0);
  for (int c = 0; c < NC; c++)
    accv = cadd(accv, cmulj(sens[(size_t)c*HW + pix], A[((size_t)(c*3+s))*HW + pix]));
  float2 b = cadd(cscale(accv, sg), cscale(mo[idx], LAMBDA_F));
  p[idx] = b; r[idx] = b; z[idx] = make_float2(0,0);
  float partv = b.x*b.x + b.y*b.y;
  for (int off = 32; off; off >>= 1) partv += __shfl_down(partv, off);
  int j = threadIdx.x & 63, w = threadIdx.x >> 6;
  if (j == 0) red[w] = partv;
  __syncthreads();
  if (threadIdx.x == 0) part[5*1024 + blockIdx.x] = red[0]+red[1]+red[2]+red[3];
}

// ---------- A: fused CG update (z,r,p) + sens-mult + row FFT (+1) -> bufA (T)
__global__ __launch_bounds__(512) void k_rows_op(const float2* __restrict__ rprev,
                                                 const float2* __restrict__ pprev,
                                                 const float2* __restrict__ Apb,
                                                 float2* __restrict__ pout,
                                                 float2* __restrict__ rout,
                                                 float2* __restrict__ z,
                                                 const float2* __restrict__ sens,
                                                 float2* __restrict__ dst,
                                                 const float* __restrict__ scal, int iter){
  __shared__ float2 tile[8][256];
  int tid = threadIdx.x, g = tid >> 6, j = tid & 63;
  float2 wA = twf((j&3)<<4), wB = twf((j&15)<<2), wC = twf(j);
  int pl = blockIdx.y, ri = blockIdx.x;
  int c = pl/3, sp = pl - 3*c;
  int row = ri*8 + g;
  int base = row*256;
  const float2* Sp = sens + (size_t)c*HW;
  float a_re=0.f, a_im=0.f, beta=0.f;
  if (iter > 0) cg_scalars(scal, iter, a_re, a_im, beta);
  size_t pb = (size_t)sp*HW + base;
  float2 pv[4];
  if (iter == 0){
    pv[0]=pprev[pb+j]; pv[1]=pprev[pb+j+64]; pv[2]=pprev[pb+j+128]; pv[3]=pprev[pb+j+192];
  } else {
    #pragma unroll
    for (int q = 0; q < 4; q++){
      int x = j + 64*q;
      float2 pe = pprev[pb+x], re_ = rprev[pb+x], ae = Apb[pb+x];
      float2 rnew = make_float2(re_.x - (a_re*ae.x - a_im*ae.y),
                                re_.y - (a_re*ae.y + a_im*ae.x));
      pv[q] = make_float2(rnew.x + beta*pe.x, rnew.y + beta*pe.y);
      if (c == 0){
        rout[pb+x] = rnew;
        pout[pb+x] = pv[q];
        float2 ze = z[pb+x];
        z[pb+x] = make_float2(ze.x + a_re*pe.x - a_im*pe.y,
                              ze.y + a_re*pe.y + a_im*pe.x);
      }
    }
  }
  float2 x0 = cmul(Sp[base+j],     pv[0]);
  float2 x1 = cmul(Sp[base+j+64],  pv[1]);
  float2 x2 = cmul(Sp[base+j+128], pv[2]);
  float2 x3 = cmul(Sp[base+j+192], pv[3]);
  fft256<1>(tile[g], j, wA,wB,wC, x0,x1,x2,x3);
  tile[g][j]=x0; tile[g][j+64]=x1; tile[g][j+128]=x2; tile[g][j+192]=x3;
  __syncthreads();
  float2* dT = dst + (size_t)pl*HW;
  int yo2 = (tid&3)*2, kxo = tid>>2;
  #pragma unroll
  for (int kb = 0; kb < 2; kb++){
    int kx = kb*128 + kxo;
    float2 a = tile[yo2][kx], b = tile[yo2+1][kx];
    *(float4*)(dT + (size_t)kx*256 + ri*8 + yo2) = make_float4(a.x,a.y,b.x,b.y);
  }
}

// ---------- B: col FFT(+1) -> 3x3 W -> col IFFT(-1); bufA contiguous -> bufB row-major
__global__ __launch_bounds__(384) void k_cols_W(const float2* __restrict__ src,
                                                float2* __restrict__ dst,
                                                const float* __restrict__ W9){
  __shared__ float2 tile[6][256];
  int tid = threadIdx.x, w = tid >> 6, j = tid & 63;
  float2 wA = twf((j&3)<<4), wB = twf((j&15)<<2), wC = twf(j);
  int kg = blockIdx.x, c = blockIdx.y;
  int s = w >> 1, kxl = w & 1;
  int kx = kg*2 + kxl;
  {
    const float2* col = src + ((size_t)(c*3+s))*HW + (size_t)kx*256;
    float2 x0=col[j], x1=col[j+64], x2=col[j+128], x3=col[j+192];
    fft256<1>(tile[w], j, wA,wB,wC, x0,x1,x2,x3);
    tile[w][j]=x0; tile[w][j+64]=x1; tile[w][j+128]=x2; tile[w][j+192]=x3;
  }
  __syncthreads();
  float2 U[4];
  #pragma unroll
  for (int q = 0; q < 4; q++){
    int k = j + 64*q;
    int wi = kx*256 + k;
    float2 v0 = tile[0*2+kxl][k], v1 = tile[1*2+kxl][k], v2 = tile[2*2+kxl][k];
    if (s == 0){
      float d0 = W9[wi];
      float2 o01 = make_float2(W9[wi+3*HW], W9[wi+4*HW]);
      float2 o02 = make_float2(W9[wi+5*HW], W9[wi+6*HW]);
      U[q] = cadd(cadd(cscale(v0,d0), cmul(o01,v1)), cmul(o02,v2));
    } else if (s == 1){
      float d1 = W9[wi+HW];
      float2 o01 = make_float2(W9[wi+3*HW], W9[wi+4*HW]);
      float2 o12 = make_float2(W9[wi+7*HW], W9[wi+8*HW]);
      U[q] = cadd(cadd(cmulj(o01,v0), cscale(v1,d1)), cmul(o12,v2));
    } else {
      float d2 = W9[wi+2*HW];
      float2 o02 = make_float2(W9[wi+5*HW], W9[wi+6*HW]);
      float2 o12 = make_float2(W9[wi+7*HW], W9[wi+8*HW]);
      U[q] = cadd(cadd(cmulj(o02,v0), cmulj(o12,v1)), cscale(v2,d2));
    }
  }
  __syncthreads();
  {
    float2 x0=U[0], x1=U[1], x2=U[2], x3=U[3];
    fft256<-1>(tile[w], j, wA,wB,wC, x0,x1,x2,x3);
    tile[w][j]=x0; tile[w][j+64]=x1; tile[w][j+128]=x2; tile[w][j+192]=x3;
  }
  __syncthreads();
  int s_out = tid >> 7, yy = tid & 127;
  #pragma unroll
  for (int yb = 0; yb < 2; yb++){
    int yc = yb*128 + yy;
    float2 a = tile[s_out*2+0][yc], b = tile[s_out*2+1][yc];
    float2* d = dst + ((size_t)(c*3+s_out))*HW;
    *(float4*)(d + (size_t)yc*256 + kg*2) = make_float4(a.x,a.y,b.x,b.y);
  }
}

// ---------- C: row IFFT(-1) + conj(S) combine + lambda*p -> Ap; per-block partials
__global__ __launch_bounds__(640) void k_rows_acc(const float2* __restrict__ Bp,
                                                  const float2* __restrict__ sens,
                                                  const float2* __restrict__ p,
                                                  const float2* __restrict__ r,
                                                  float2* __restrict__ Ap,
                                                  float* __restrict__ part){
  __shared__ float2 scratch[10][256];
  __shared__ float red5[4][5];
  int tid = threadIdx.x, w = tid >> 6, j = tid & 63;
  float2 wA = twf((j&3)<<4), wB = twf((j&15)<<2), wC = twf(j);
  int row = blockIdx.x, s = blockIdx.y;
  {
    int c = w;
    const float2* src = Bp + ((size_t)(c*3+s))*HW + row*256;
    float2 x0=src[j], x1=src[j+64], x2=src[j+128], x3=src[j+192];
    fft256<-1>(scratch[w], j, wA,wB,wC, x0,x1,x2,x3);
    const float2* Sc = sens + (size_t)c*HW + row*256;
    scratch[w][j]     = cmulj(Sc[j],     x0);
    scratch[w][j+64]  = cmulj(Sc[j+64],  x1);
    scratch[w][j+128] = cmulj(Sc[j+128], x2);
    scratch[w][j+192] = cmulj(Sc[j+192], x3);
  }
  __syncthreads();
  if (tid < 256){
    int k = tid;
    float2 a = make_float2(0,0);
    #pragma unroll
    for (int c = 0; c < NC; c++) a = cadd(a, scratch[c][k]);
    size_t ob = (size_t)s*HW + row*256 + k;
    float2 pv = p[ob];
    float2 ap = cadd(a, cscale(pv, LAMBDA_F));
    Ap[ob] = ap;
    float2 rv = r[ob];
    float s0 = pv.x*ap.x + pv.y*ap.y;   // pAp.re
    float s1 = pv.x*ap.y - pv.y*ap.x;   // pAp.im
    float s2 = rv.x*ap.x + rv.y*ap.y;   // rAp.re
    float s3 = rv.x*ap.y - rv.y*ap.x;   // rAp.im
    float s4 = ap.x*ap.x + ap.y*ap.y;   // |Ap|^2
    for (int off = 32; off; off >>= 1){
      s0 += __shfl_down(s0, off); s1 += __shfl_down(s1, off);
      s2 += __shfl_down(s2, off); s3 += __shfl_down(s3, off);
      s4 += __shfl_down(s4, off);
    }
    if (j == 0){ red5[w][0]=s0; red5[w][1]=s1; red5[w][2]=s2; red5[w][3]=s3; red5[w][4]=s4; }
  }
  __syncthreads();
  if (tid == 0){
    int bflat = blockIdx.y*256 + blockIdx.x;   // 0..767
    #pragma unroll
    for (int q = 0; q < 5; q++)
      part[q*1024 + bflat] = red5[0][q]+red5[1][q]+red5[2][q]+red5[3][q];
  }
}

// ---------- tiny serial reduce: 768 partials x5 -> scal[8+8it+..]; it0 also rs0
__global__ __launch_bounds__(256) void k_reduce(float* __restrict__ scal,
                                                const float* __restrict__ part, int iter){
  __shared__ float red[4];
  int tid = threadIdx.x, j = tid & 63, w = tid >> 6;
  for (int q = 0; q < 5; q++){
    float v = part[q*1024 + tid] + part[q*1024 + tid + 256] + part[q*1024 + tid + 512];
    for (int off = 32; off; off >>= 1) v += __shfl_down(v, off);
    if (j == 0) red[w] = v;
    __syncthreads();
    if (tid == 0) scal[8+8*iter+q] = red[0]+red[1]+red[2]+red[3];
    __syncthreads();
  }
  if (iter == 0){
    float v = part[5*1024 + tid] + part[5*1024 + tid + 256] + part[5*1024 + tid + 512];
    for (int off = 32; off; off >>= 1) v += __shfl_down(v, off);
    if (j == 0) red[w] = v;
    __syncthreads();
    if (tid == 0) scal[0] = red[0]+red[1]+red[2]+red[3];
  }
}

// ---------- final: z += alpha_9 * p_9
__global__ __launch_bounds__(256) void k_zfin(float2* __restrict__ z,
                                              const float2* __restrict__ p9,
                                              const float* __restrict__ scal){
  float a_re, a_im, beta;
  cg_scalars(scal, 10, a_re, a_im, beta);
  int idx = blockIdx.x*256 + threadIdx.x;
  float2 pe = p9[idx], ze = z[idx];
  z[idx] = make_float2(ze.x + a_re*pe.x - a_im*pe.y,
                       ze.y + a_re*pe.y + a_im*pe.x);
}

extern "C" void kernel_launch(void* const* d_in, const int* in_sizes, int n_in,
                              void* d_out, int out_size, void* d_ws, size_t ws_size,
                              hipStream_t stream){
  const float2* y    = (const float2*)d_in[0];
  const float2* mo   = (const float2*)d_in[1];
  const float2* sens = (const float2*)d_in[2];
  const float2* Lt   = (const float2*)d_in[3];
  const float*  mask = (const float*)d_in[4];

  float* w = (float*)d_ws;
  float*  scal = w;                                  // 128 floats
  float*  part = w + 128;                            // 6*1024 floats (block partials)
  float*  W9   = w + 128 + 6144;                     // 9*HW floats
  float2* bufA = (float2*)(W9 + 9*HW);               // 30 planes (transposed k-space)
  float2* bufB = bufA + (size_t)30*HW;               // 30 planes (row-major)
  float2* p0   = bufB + (size_t)30*HW;
  float2* p1   = p0 + (size_t)3*HW;
  float2* r0   = p1 + (size_t)3*HW;
  float2* r1   = r0 + (size_t)3*HW;
  float2* Ap   = r1 + (size_t)3*HW;
  float2* z    = (float2*)d_out;

  // setup
  k_setup<<<2816, 256, 0, stream>>>(mask, Lt, y, W9, bufB);
  k_rows_plain<<<dim3(32, 30), 512, 0, stream>>>(bufB, bufA);
  k_cols_plain<<<dim3(32, 30), 512, 0, stream>>>(bufA, bufB);
  k_compute_b<<<768, 256, 0, stream>>>(bufB, sens, mo, p0, r0, z, part);

  // CG iterations: 3 compute kernels + tiny reduce each
  for (int it = 0; it < 10; it++){
    float2* pprev = (it == 0) ? p0 : ((it & 1) ? p0 : p1);
    float2* rprev = (it == 0) ? r0 : ((it & 1) ? r0 : r1);
    float2* pw = (it & 1) ? p1 : p0;   // p_it
    float2* rw = (it & 1) ? r1 : r0;   // r_it
    k_rows_op<<<dim3(32, 30), 512, 0, stream>>>(rprev, pprev, Ap, pw, rw, z, sens, bufA, scal, it);
    k_cols_W<<<dim3(128, 10), 384, 0, stream>>>(bufA, bufB, W9);
    k_rows_acc<<<dim3(256, 3), 640, 0, stream>>>(bufB, sens, pw, rw, Ap, part);
    k_reduce<<<1, 256, 0, stream>>>(scal, part, it);
  }
  k_zfin<<<768, 256, 0, stream>>>(z, p1, scal);
}

// Round 8
// 474.080 us; speedup vs baseline: 1.9052x; 1.0032x over previous
//
#include <hip/hip_runtime.h>
#include <math.h>

#define HW 65536
#define NC 10
#define NT 12
#define LAMBDA_F 0.05f
#define PI_F 3.14159265358979323846f
// XOR-swizzle for wave-private LDS fft scratch
#define SWZ(i) ((i) ^ ((i) >> 4))

__device__ __forceinline__ float2 cadd(float2 a, float2 b){ return make_float2(a.x+b.x, a.y+b.y); }
__device__ __forceinline__ float2 csub(float2 a, float2 b){ return make_float2(a.x-b.x, a.y-b.y); }
__device__ __forceinline__ float2 cmul(float2 a, float2 b){ return make_float2(a.x*b.x-a.y*b.y, a.x*b.y+a.y*b.x); }
// conj(a)*b
__device__ __forceinline__ float2 cmulj(float2 a, float2 b){ return make_float2(a.x*b.x+a.y*b.y, a.x*b.y-a.y*b.x); }
__device__ __forceinline__ float2 cscale(float2 a, float s){ return make_float2(a.x*s, a.y*s); }

template<int SIGN>
__device__ __forceinline__ void radix4_nt(float2& a0, float2& a1, float2& a2, float2& a3){
  float2 t0=cadd(a0,a2), t1=csub(a0,a2), t2=cadd(a1,a3), t3=csub(a1,a3);
  float2 t3r;
  if constexpr (SIGN < 0) t3r = make_float2(t3.y, -t3.x); else t3r = make_float2(-t3.y, t3.x);
  a0=cadd(t0,t2); a1=cadd(t1,t3r); a2=csub(t0,t2); a3=csub(t1,t3r);
}

template<int SIGN>
__device__ __forceinline__ void radix4_tw(float2& a0, float2& a1, float2& a2, float2& a3, float2 w){
  if constexpr (SIGN > 0) w.y = -w.y;
  float2 w2 = cmul(w, w);
  float2 w3 = cmul(w, w2);
  a1 = cmul(a1, w); a2 = cmul(a2, w2); a3 = cmul(a3, w3);
  radix4_nt<SIGN>(a0, a1, a2, a3);
}

__device__ __forceinline__ float2 twf(int e){
  float s, c;
  __sincosf(-2.0f*PI_F*(float)e*(1.0f/256.0f), &s, &c);
  return make_float2(c, s);
}

// Single 256-pt Stockham radix-4 FFT (setup kernels).
template<int SIGN>
__device__ __forceinline__ void fft256(float2* b, int j,
                                       float2 wA, float2 wB, float2 wC,
                                       float2& x0, float2& x1, float2& x2, float2& x3){
  radix4_nt<SIGN>(x0,x1,x2,x3);
  b[SWZ(4*j)]=x0; b[SWZ(4*j+1)]=x1; b[SWZ(4*j+2)]=x2; b[SWZ(4*j+3)]=x3;
  x0=b[SWZ(j)]; x1=b[SWZ(j+64)]; x2=b[SWZ(j+128)]; x3=b[SWZ(j+192)];
  radix4_tw<SIGN>(x0,x1,x2,x3, wA);
  { int i=((j>>2)<<4)+(j&3); b[SWZ(i)]=x0; b[SWZ(i+4)]=x1; b[SWZ(i+8)]=x2; b[SWZ(i+12)]=x3; }
  x0=b[SWZ(j)]; x1=b[SWZ(j+64)]; x2=b[SWZ(j+128)]; x3=b[SWZ(j+192)];
  radix4_tw<SIGN>(x0,x1,x2,x3, wB);
  { int i=((j>>4)<<6)+(j&15); b[SWZ(i)]=x0; b[SWZ(i+16)]=x1; b[SWZ(i+32)]=x2; b[SWZ(i+48)]=x3; }
  x0=b[SWZ(j)]; x1=b[SWZ(j+64)]; x2=b[SWZ(j+128)]; x3=b[SWZ(j+192)];
  radix4_tw<SIGN>(x0,x1,x2,x3, wC);
}

// TWO independent 256-pt FFTs, stage-interleaved on disjoint wave-private
// scratch: FFT-B's LDS ops issue under FFT-A's LDS latency (2x ILP per wave).
template<int SIGN>
__device__ __forceinline__ void fft256x2(float2* bA, float2* bB, int j,
    float2 wA, float2 wB, float2 wC,
    float2& a0, float2& a1, float2& a2, float2& a3,
    float2& b0, float2& b1, float2& b2, float2& b3){
  radix4_nt<SIGN>(a0,a1,a2,a3); radix4_nt<SIGN>(b0,b1,b2,b3);
  bA[SWZ(4*j)]=a0; bA[SWZ(4*j+1)]=a1; bA[SWZ(4*j+2)]=a2; bA[SWZ(4*j+3)]=a3;
  bB[SWZ(4*j)]=b0; bB[SWZ(4*j+1)]=b1; bB[SWZ(4*j+2)]=b2; bB[SWZ(4*j+3)]=b3;
  a0=bA[SWZ(j)]; a1=bA[SWZ(j+64)]; a2=bA[SWZ(j+128)]; a3=bA[SWZ(j+192)];
  b0=bB[SWZ(j)]; b1=bB[SWZ(j+64)]; b2=bB[SWZ(j+128)]; b3=bB[SWZ(j+192)];
  radix4_tw<SIGN>(a0,a1,a2,a3, wA); radix4_tw<SIGN>(b0,b1,b2,b3, wA);
  { int i=((j>>2)<<4)+(j&3);
    bA[SWZ(i)]=a0; bA[SWZ(i+4)]=a1; bA[SWZ(i+8)]=a2; bA[SWZ(i+12)]=a3;
    bB[SWZ(i)]=b0; bB[SWZ(i+4)]=b1; bB[SWZ(i+8)]=b2; bB[SWZ(i+12)]=b3; }
  a0=bA[SWZ(j)]; a1=bA[SWZ(j+64)]; a2=bA[SWZ(j+128)]; a3=bA[SWZ(j+192)];
  b0=bB[SWZ(j)]; b1=bB[SWZ(j+64)]; b2=bB[SWZ(j+128)]; b3=bB[SWZ(j+192)];
  radix4_tw<SIGN>(a0,a1,a2,a3, wB); radix4_tw<SIGN>(b0,b1,b2,b3, wB);
  { int i=((j>>4)<<6)+(j&15);
    bA[SWZ(i)]=a0; bA[SWZ(i+16)]=a1; bA[SWZ(i+32)]=a2; bA[SWZ(i+48)]=a3;
    bB[SWZ(i)]=b0; bB[SWZ(i+16)]=b1; bB[SWZ(i+32)]=b2; bB[SWZ(i+48)]=b3; }
  a0=bA[SWZ(j)]; a1=bA[SWZ(j+64)]; a2=bA[SWZ(j+128)]; a3=bA[SWZ(j+192)];
  b0=bB[SWZ(j)]; b1=bB[SWZ(j+64)]; b2=bB[SWZ(j+128)]; b3=bB[SWZ(j+192)];
  radix4_tw<SIGN>(a0,a1,a2,a3, wC); radix4_tw<SIGN>(b0,b1,b2,b3, wC);
}

// CG scalar chain with the freshest tuple passed in registers.
// scal: [0]=rs0 ; tuple k at scal[8+8k..]: pAp.re, pAp.im, rAp.re, rAp.im, |Ap|^2
__device__ __forceinline__ void cg_chain(const float* __restrict__ scal,
                                         float f0, float f1, float f2, float f3, float f4,
                                         float rs0, int it,
                                         float& a_re, float& a_im, float& beta){
  float rs = rs0; a_re = 0.f; a_im = 0.f; beta = 0.f;
  for (int k = 0; k < it; k++){
    float pr, pi, rr_, ri_, aa;
    if (k == it-1){ pr=f0; pi=f1; rr_=f2; ri_=f3; aa=f4; }
    else { pr=scal[8+8*k+0]; pi=scal[8+8*k+1]; rr_=scal[8+8*k+2];
           ri_=scal[8+8*k+3]; aa=scal[8+8*k+4]; }
    float den = pr*pr + pi*pi;
    a_re =  rs*pr/den;
    a_im = -rs*pi/den;
    float re_ = a_re*rr_ - a_im*ri_;
    float rs_next = rs - 2.0f*re_ + (a_re*a_re + a_im*a_im)*aa;
    beta = rs_next/rs;
    rs = rs_next;
  }
}

// ---------- S0: W9 precompute + g = D*sum_t conj(L) y (into bufB) + zero scal/part
__global__ __launch_bounds__(256) void k_setup(const float* __restrict__ mask,
                                               const float2* __restrict__ Lt,
                                               const float2* __restrict__ y,
                                               float* __restrict__ W9,
                                               float2* __restrict__ bufB,
                                               float* __restrict__ scal,
                                               float* __restrict__ part){
  int tid = threadIdx.x;
  int u = blockIdx.x;
  if (u == 0){
    if (tid < 128) scal[tid] = 0.0f;
    for (int i = tid; i < 6144; i += 256) part[i] = 0.0f;
  }
  if (u < 256){
    int kx = u, ky = tid;
    int mx = (kx + 128) & 255, my = (ky + 128) & 255;
    float d0=0.f,d1=0.f,d2=0.f;
    float2 o01=make_float2(0,0), o02=make_float2(0,0), o12=make_float2(0,0);
    for (int t = 0; t < NT; t++){
      float m = mask[t*HW + my*256 + mx];
      float2 l0 = Lt[t*3+0], l1 = Lt[t*3+1], l2 = Lt[t*3+2];
      d0 += m*(l0.x*l0.x + l0.y*l0.y);
      d1 += m*(l1.x*l1.x + l1.y*l1.y);
      d2 += m*(l2.x*l2.x + l2.y*l2.y);
      o01 = cadd(o01, cscale(cmulj(l0,l1), m));
      o02 = cadd(o02, cscale(cmulj(l0,l2), m));
      o12 = cadd(o12, cscale(cmulj(l1,l2), m));
    }
    const float nrm = 1.0f/65536.0f;
    int idx = kx*256 + ky;
    W9[idx]      = d0*nrm;  W9[idx+HW]   = d1*nrm;  W9[idx+2*HW] = d2*nrm;
    W9[idx+3*HW] = o01.x*nrm; W9[idx+4*HW] = o01.y*nrm;
    W9[idx+5*HW] = o02.x*nrm; W9[idx+6*HW] = o02.y*nrm;
    W9[idx+7*HW] = o12.x*nrm; W9[idx+8*HW] = o12.y*nrm;
  } else {
    int idx = (u-256)*256 + tid;
    int c = idx >> 16, pix = idx & (HW-1);
    int xx = pix & 255, yy2 = pix >> 8;
    float sg = ((xx + yy2) & 1) ? -1.0f : 1.0f;
    float2 a0=make_float2(0,0), a1=make_float2(0,0), a2=make_float2(0,0);
    for (int t = 0; t < NT; t++){
      float2 yv = y[((size_t)(t*NC + c))*HW + pix];
      a0 = cadd(a0, cmulj(Lt[t*3+0], yv));
      a1 = cadd(a1, cmulj(Lt[t*3+1], yv));
      a2 = cadd(a2, cmulj(Lt[t*3+2], yv));
    }
    bufB[((size_t)(c*3+0))*HW + pix] = cscale(a0, sg);
    bufB[((size_t)(c*3+1))*HW + pix] = cscale(a1, sg);
    bufB[((size_t)(c*3+2))*HW + pix] = cscale(a2, sg);
  }
}

// ---------- setup row IFFT (-1): bufB row-major -> bufA transposed [pl][kx][y]
__global__ __launch_bounds__(512) void k_rows_plain(const float2* __restrict__ src,
                                                    float2* __restrict__ dst){
  __shared__ float2 tile[8][256];
  int tid = threadIdx.x, g = tid >> 6, j = tid & 63;
  float2 wA = twf((j&3)<<4), wB = twf((j&15)<<2), wC = twf(j);
  int pl = blockIdx.y, ri = blockIdx.x;
  int row = ri*8 + g;
  const float2* sr = src + (size_t)pl*HW + row*256;
  float2 x0=sr[j], x1=sr[j+64], x2=sr[j+128], x3=sr[j+192];
  fft256<-1>(tile[g], j, wA,wB,wC, x0,x1,x2,x3);
  tile[g][j]=x0; tile[g][j+64]=x1; tile[g][j+128]=x2; tile[g][j+192]=x3;
  __syncthreads();
  float2* dT = dst + (size_t)pl*HW;
  int yo2 = (tid&3)*2, kxo = tid>>2;
  #pragma unroll
  for (int kb = 0; kb < 2; kb++){
    int kx = kb*128 + kxo;
    float2 a = tile[yo2][kx], b = tile[yo2+1][kx];
    *(float4*)(dT + (size_t)kx*256 + ri*8 + yo2) = make_float4(a.x,a.y,b.x,b.y);
  }
}

// ---------- setup col IFFT (-1): bufA [pl][kx][y] contiguous -> bufB row-major
__global__ __launch_bounds__(512) void k_cols_plain(const float2* __restrict__ src,
                                                    float2* __restrict__ dst){
  __shared__ float2 tile[8][256];
  int tid = threadIdx.x, g = tid >> 6, j = tid & 63;
  float2 wA = twf((j&3)<<4), wB = twf((j&15)<<2), wC = twf(j);
  int pl = blockIdx.y, kg = blockIdx.x;
  int kx = kg*8 + g;
  const float2* col = src + (size_t)pl*HW + (size_t)kx*256;
  float2 x0=col[j], x1=col[j+64], x2=col[j+128], x3=col[j+192];
  fft256<-1>(tile[g], j, wA,wB,wC, x0,x1,x2,x3);
  tile[g][j]=x0; tile[g][j+64]=x1; tile[g][j+128]=x2; tile[g][j+192]=x3;
  __syncthreads();
  float2* d = dst + (size_t)pl*HW;
  int kxo2 = (tid&3)*2, yy = tid>>2;
  #pragma unroll
  for (int yb = 0; yb < 2; yb++){
    int yc = yb*128 + yy;
    float2 a = tile[kxo2][yc], b = tile[kxo2+1][yc];
    *(float4*)(d + (size_t)yc*256 + kg*8 + kxo2) = make_float4(a.x,a.y,b.x,b.y);
  }
}

// ---------- b = D * sum_c conj(S_c) * bufB + lambda*mo ; p=r=b ; z=0 ; rs0 partial
__global__ __launch_bounds__(256) void k_compute_b(const float2* __restrict__ A,
                                                   const float2* __restrict__ sens,
                                                   const float2* __restrict__ mo,
                                                   float2* __restrict__ p,
                                                   float2* __restrict__ r,
                                                   float2* __restrict__ z,
                                                   float* __restrict__ part){
  __shared__ float red[4];
  int idx = blockIdx.x*256 + threadIdx.x;
  int s = idx >> 16, pix = idx & (HW-1);
  int xx = pix & 255, yy = pix >> 8;
  float sg = ((xx + yy) & 1) ? -1.0f : 1.0f;
  float2 accv = make_float2(0,0);
  for (int c = 0; c < NC; c++)
    accv = cadd(accv, cmulj(sens[(size_t)c*HW + pix], A[((size_t)(c*3+s))*HW + pix]));
  float2 b = cadd(cscale(accv, sg), cscale(mo[idx], LAMBDA_F));
  p[idx] = b; r[idx] = b; z[idx] = make_float2(0,0);
  float partv = b.x*b.x + b.y*b.y;
  for (int off = 32; off; off >>= 1) partv += __shfl_down(partv, off);
  int j = threadIdx.x & 63, w = threadIdx.x >> 6;
  if (j == 0) red[w] = partv;
  __syncthreads();
  if (threadIdx.x == 0) part[5*1024 + blockIdx.x] = red[0]+red[1]+red[2]+red[3];
}

// ---------- A: inline scalar reduce + CG update (z,r,p) + sens-mult + row FFT(+1)
// 256 threads = 4 waves x 2 rows (interleaved FFT pair per wave).
__global__ __launch_bounds__(256) void k_rows_op(const float2* __restrict__ rprev,
                                                 const float2* __restrict__ pprev,
                                                 const float2* __restrict__ Apb,
                                                 float2* __restrict__ pout,
                                                 float2* __restrict__ rout,
                                                 float2* __restrict__ z,
                                                 const float2* __restrict__ sens,
                                                 float2* __restrict__ dst,
                                                 float* __restrict__ scal,
                                                 const float* __restrict__ part,
                                                 int iter){
  __shared__ float2 tile[8][256];
  __shared__ float red6[4][6];
  int tid = threadIdx.x, g = tid >> 6, j = tid & 63;
  float2 wA = twf((j&3)<<4), wB = twf((j&15)<<2), wC = twf(j);
  int pl = blockIdx.y, ri = blockIdx.x;
  int c = pl/3, sp = pl - 3*c;
  const float2* Sp = sens + (size_t)c*HW;

  float a_re=0.f, a_im=0.f, beta=0.f;
  if (iter > 0){
    // redundant block-local reduce of per-block partials (L2-resident)
    float v[6];
    #pragma unroll
    for (int q = 0; q < 6; q++){
      float x = part[q*1024+tid] + part[q*1024+tid+256]
              + part[q*1024+tid+512] + part[q*1024+tid+768];
      for (int off = 32; off; off >>= 1) x += __shfl_down(x, off);
      v[q] = x;
    }
    if (j == 0){
      #pragma unroll
      for (int q = 0; q < 6; q++) red6[g][q] = v[q];
    }
    __syncthreads();
    float f0 = red6[0][0]+red6[1][0]+red6[2][0]+red6[3][0];
    float f1 = red6[0][1]+red6[1][1]+red6[2][1]+red6[3][1];
    float f2 = red6[0][2]+red6[1][2]+red6[2][2]+red6[3][2];
    float f3 = red6[0][3]+red6[1][3]+red6[2][3]+red6[3][3];
    float f4 = red6[0][4]+red6[1][4]+red6[2][4]+red6[3][4];
    float rs0 = (iter == 1) ? (red6[0][5]+red6[1][5]+red6[2][5]+red6[3][5]) : scal[0];
    cg_chain(scal, f0,f1,f2,f3,f4, rs0, iter, a_re, a_im, beta);
    if (blockIdx.x == 0 && blockIdx.y == 0 && tid == 0){
      scal[8+8*(iter-1)+0]=f0; scal[8+8*(iter-1)+1]=f1; scal[8+8*(iter-1)+2]=f2;
      scal[8+8*(iter-1)+3]=f3; scal[8+8*(iter-1)+4]=f4;
      if (iter == 1) scal[0] = rs0;
    }
  }

  int row0 = ri*8 + g*2, row1 = row0 + 1;
  int baseA = row0*256, baseB = row1*256;
  size_t pbA = (size_t)sp*HW + baseA, pbB = (size_t)sp*HW + baseB;
  float2 pvA[4], pvB[4];
  if (iter == 0){
    #pragma unroll
    for (int q = 0; q < 4; q++){
      pvA[q] = pprev[pbA + j + 64*q];
      pvB[q] = pprev[pbB + j + 64*q];
    }
  } else {
    #pragma unroll
    for (int q = 0; q < 4; q++){
      int x = j + 64*q;
      float2 peA = pprev[pbA+x], reA = rprev[pbA+x], aeA = Apb[pbA+x];
      float2 peB = pprev[pbB+x], reB = rprev[pbB+x], aeB = Apb[pbB+x];
      float2 rnA = make_float2(reA.x - (a_re*aeA.x - a_im*aeA.y),
                               reA.y - (a_re*aeA.y + a_im*aeA.x));
      float2 rnB = make_float2(reB.x - (a_re*aeB.x - a_im*aeB.y),
                               reB.y - (a_re*aeB.y + a_im*aeB.x));
      pvA[q] = make_float2(rnA.x + beta*peA.x, rnA.y + beta*peA.y);
      pvB[q] = make_float2(rnB.x + beta*peB.x, rnB.y + beta*peB.y);
      if (c == 0){
        rout[pbA+x] = rnA;  rout[pbB+x] = rnB;
        pout[pbA+x] = pvA[q]; pout[pbB+x] = pvB[q];
        float2 zA = z[pbA+x], zB = z[pbB+x];
        z[pbA+x] = make_float2(zA.x + a_re*peA.x - a_im*peA.y,
                               zA.y + a_re*peA.y + a_im*peA.x);
        z[pbB+x] = make_float2(zB.x + a_re*peB.x - a_im*peB.y,
                               zB.y + a_re*peB.y + a_im*peB.x);
      }
    }
  }
  float2 xA0 = cmul(Sp[baseA+j],     pvA[0]);
  float2 xA1 = cmul(Sp[baseA+j+64],  pvA[1]);
  float2 xA2 = cmul(Sp[baseA+j+128], pvA[2]);
  float2 xA3 = cmul(Sp[baseA+j+192], pvA[3]);
  float2 xB0 = cmul(Sp[baseB+j],     pvB[0]);
  float2 xB1 = cmul(Sp[baseB+j+64],  pvB[1]);
  float2 xB2 = cmul(Sp[baseB+j+128], pvB[2]);
  float2 xB3 = cmul(Sp[baseB+j+192], pvB[3]);
  fft256x2<1>(tile[g*2], tile[g*2+1], j, wA,wB,wC, xA0,xA1,xA2,xA3, xB0,xB1,xB2,xB3);
  tile[g*2][j]=xA0; tile[g*2][j+64]=xA1; tile[g*2][j+128]=xA2; tile[g*2][j+192]=xA3;
  tile[g*2+1][j]=xB0; tile[g*2+1][j+64]=xB1; tile[g*2+1][j+128]=xB2; tile[g*2+1][j+192]=xB3;
  __syncthreads();
  float2* dT = dst + (size_t)pl*HW;
  int yo2 = (tid&3)*2, kxo = tid>>2;
  #pragma unroll
  for (int kb = 0; kb < 4; kb++){
    int kx = kb*64 + kxo;
    float2 a = tile[yo2][kx], b = tile[yo2+1][kx];
    *(float4*)(dT + (size_t)kx*256 + ri*8 + yo2) = make_float4(a.x,a.y,b.x,b.y);
  }
}

// ---------- B: col FFT(+1) -> 3x3 W -> col IFFT(-1); 4 kx per block.
// 384 threads = 6 waves: wave (s = w>>1, kxp = w&1) handles kx pair (interleaved).
__global__ __launch_bounds__(384) void k_cols_W(const float2* __restrict__ src,
                                                float2* __restrict__ dst,
                                                const float* __restrict__ W9){
  __shared__ float2 tile[12][256];   // [s*4 + kxl][y]
  int tid = threadIdx.x, w = tid >> 6, j = tid & 63;
  float2 wA = twf((j&3)<<4), wB = twf((j&15)<<2), wC = twf(j);
  int kg = blockIdx.x, c = blockIdx.y;
  int s = w >> 1, kxp = w & 1;
  int kxl0 = kxp*2, kxl1 = kxl0+1;
  int kx0 = kg*4 + kxl0, kx1 = kg*4 + kxl1;
  {
    const float2* colA = src + ((size_t)(c*3+s))*HW + (size_t)kx0*256;
    const float2* colB = src + ((size_t)(c*3+s))*HW + (size_t)kx1*256;
    float2 a0=colA[j], a1=colA[j+64], a2=colA[j+128], a3=colA[j+192];
    float2 b0=colB[j], b1=colB[j+64], b2=colB[j+128], b3=colB[j+192];
    fft256x2<1>(tile[s*4+kxl0], tile[s*4+kxl1], j, wA,wB,wC, a0,a1,a2,a3, b0,b1,b2,b3);
    tile[s*4+kxl0][j]=a0; tile[s*4+kxl0][j+64]=a1; tile[s*4+kxl0][j+128]=a2; tile[s*4+kxl0][j+192]=a3;
    tile[s*4+kxl1][j]=b0; tile[s*4+kxl1][j+64]=b1; tile[s*4+kxl1][j+128]=b2; tile[s*4+kxl1][j+192]=b3;
  }
  __syncthreads();
  float2 UA[4], UB[4];
  #pragma unroll
  for (int q = 0; q < 4; q++){
    int k = j + 64*q;
    // kx0
    {
      int wi = kx0*256 + k;
      float2 v0 = tile[0+kxl0][k], v1 = tile[4+kxl0][k], v2 = tile[8+kxl0][k];
      if (s == 0){
        float d0 = W9[wi];
        float2 o01 = make_float2(W9[wi+3*HW], W9[wi+4*HW]);
        float2 o02 = make_float2(W9[wi+5*HW], W9[wi+6*HW]);
        UA[q] = cadd(cadd(cscale(v0,d0), cmul(o01,v1)), cmul(o02,v2));
      } else if (s == 1){
        float d1 = W9[wi+HW];
        float2 o01 = make_float2(W9[wi+3*HW], W9[wi+4*HW]);
        float2 o12 = make_float2(W9[wi+7*HW], W9[wi+8*HW]);
        UA[q] = cadd(cadd(cmulj(o01,v0), cscale(v1,d1)), cmul(o12,v2));
      } else {
        float d2 = W9[wi+2*HW];
        float2 o02 = make_float2(W9[wi+5*HW], W9[wi+6*HW]);
        float2 o12 = make_float2(W9[wi+7*HW], W9[wi+8*HW]);
        UA[q] = cadd(cadd(cmulj(o02,v0), cmulj(o12,v1)), cscale(v2,d2));
      }
    }
    // kx1
    {
      int wi = kx1*256 + k;
      float2 v0 = tile[0+kxl1][k], v1 = tile[4+kxl1][k], v2 = tile[8+kxl1][k];
      if (s == 0){
        float d0 = W9[wi];
        float2 o01 = make_float2(W9[wi+3*HW], W9[wi+4*HW]);
        float2 o02 = make_float2(W9[wi+5*HW], W9[wi+6*HW]);
        UB[q] = cadd(cadd(cscale(v0,d0), cmul(o01,v1)), cmul(o02,v2));
      } else if (s == 1){
        float d1 = W9[wi+HW];
        float2 o01 = make_float2(W9[wi+3*HW], W9[wi+4*HW]);
        float2 o12 = make_float2(W9[wi+7*HW], W9[wi+8*HW]);
        UB[q] = cadd(cadd(cmulj(o01,v0), cscale(v1,d1)), cmul(o12,v2));
      } else {
        float d2 = W9[wi+2*HW];
        float2 o02 = make_float2(W9[wi+5*HW], W9[wi+6*HW]);
        float2 o12 = make_float2(W9[wi+7*HW], W9[wi+8*HW]);
        UB[q] = cadd(cadd(cmulj(o02,v0), cmulj(o12,v1)), cscale(v2,d2));
      }
    }
  }
  __syncthreads();   // all combine reads done before tile reused as scratch
  {
    float2 a0=UA[0], a1=UA[1], a2=UA[2], a3=UA[3];
    float2 b0=UB[0], b1=UB[1], b2=UB[2], b3=UB[3];
    fft256x2<-1>(tile[s*4+kxl0], tile[s*4+kxl1], j, wA,wB,wC, a0,a1,a2,a3, b0,b1,b2,b3);
    tile[s*4+kxl0][j]=a0; tile[s*4+kxl0][j+64]=a1; tile[s*4+kxl0][j+128]=a2; tile[s*4+kxl0][j+192]=a3;
    tile[s*4+kxl1][j]=b0; tile[s*4+kxl1][j+64]=b1; tile[s*4+kxl1][j+128]=b2; tile[s*4+kxl1][j+192]=b3;
  }
  __syncthreads();
  // transposed write row-major: 1536 float4 over 384 threads
  #pragma unroll
  for (int yb = 0; yb < 4; yb++){
    int flat = yb*384 + tid;
    int s_out = flat >> 9;
    int rem = flat & 511;
    int kxo2 = (rem >> 8) << 1;
    int yc = rem & 255;
    float2 a = tile[s_out*4+kxo2][yc], b = tile[s_out*4+kxo2+1][yc];
    float2* d = dst + ((size_t)(c*3+s_out))*HW;
    *(float4*)(d + (size_t)yc*256 + kg*4 + kxo2) = make_float4(a.x,a.y,b.x,b.y);
  }
}

// ---------- C: row IFFT(-1) + conj(S) combine + lambda*p -> Ap; per-block partials
// 320 threads = 5 waves x 2 coils (interleaved FFT pair per wave).
__global__ __launch_bounds__(320) void k_rows_acc(const float2* __restrict__ Bp,
                                                  const float2* __restrict__ sens,
                                                  const float2* __restrict__ p,
                                                  const float2* __restrict__ r,
                                                  float2* __restrict__ Ap,
                                                  float* __restrict__ part){
  __shared__ float2 scratch[10][256];
  __shared__ float red5[4][5];
  int tid = threadIdx.x, w = tid >> 6, j = tid & 63;
  float2 wA = twf((j&3)<<4), wB = twf((j&15)<<2), wC = twf(j);
  int row = blockIdx.x, s = blockIdx.y;
  {
    int c0 = 2*w, c1 = 2*w+1;
    const float2* srcA = Bp + ((size_t)(c0*3+s))*HW + row*256;
    const float2* srcB = Bp + ((size_t)(c1*3+s))*HW + row*256;
    float2 a0=srcA[j], a1=srcA[j+64], a2=srcA[j+128], a3=srcA[j+192];
    float2 b0=srcB[j], b1=srcB[j+64], b2=srcB[j+128], b3=srcB[j+192];
    fft256x2<-1>(scratch[c0], scratch[c1], j, wA,wB,wC, a0,a1,a2,a3, b0,b1,b2,b3);
    const float2* ScA = sens + (size_t)c0*HW + row*256;
    const float2* ScB = sens + (size_t)c1*HW + row*256;
    scratch[c0][j]     = cmulj(ScA[j],     a0);
    scratch[c0][j+64]  = cmulj(ScA[j+64],  a1);
    scratch[c0][j+128] = cmulj(ScA[j+128], a2);
    scratch[c0][j+192] = cmulj(ScA[j+192], a3);
    scratch[c1][j]     = cmulj(ScB[j],     b0);
    scratch[c1][j+64]  = cmulj(ScB[j+64],  b1);
    scratch[c1][j+128] = cmulj(ScB[j+128], b2);
    scratch[c1][j+192] = cmulj(ScB[j+192], b3);
  }
  __syncthreads();
  if (tid < 256){
    int k = tid;
    float2 a = make_float2(0,0);
    #pragma unroll
    for (int c = 0; c < NC; c++) a = cadd(a, scratch[c][k]);
    size_t ob = (size_t)s*HW + row*256 + k;
    float2 pv = p[ob];
    float2 ap = cadd(a, cscale(pv, LAMBDA_F));
    Ap[ob] = ap;
    float2 rv = r[ob];
    float s0 = pv.x*ap.x + pv.y*ap.y;   // pAp.re
    float s1 = pv.x*ap.y - pv.y*ap.x;   // pAp.im
    float s2 = rv.x*ap.x + rv.y*ap.y;   // rAp.re
    float s3 = rv.x*ap.y - rv.y*ap.x;   // rAp.im
    float s4 = ap.x*ap.x + ap.y*ap.y;   // |Ap|^2
    for (int off = 32; off; off >>= 1){
      s0 += __shfl_down(s0, off); s1 += __shfl_down(s1, off);
      s2 += __shfl_down(s2, off); s3 += __shfl_down(s3, off);
      s4 += __shfl_down(s4, off);
    }
    if (j == 0){ red5[w][0]=s0; red5[w][1]=s1; red5[w][2]=s2; red5[w][3]=s3; red5[w][4]=s4; }
  }
  __syncthreads();
  if (tid == 0){
    int bflat = blockIdx.y*256 + blockIdx.x;   // 0..767
    #pragma unroll
    for (int q = 0; q < 5; q++)
      part[q*1024 + bflat] = red5[0][q]+red5[1][q]+red5[2][q]+red5[3][q];
  }
}

// ---------- final: z += alpha_9 * p_9 (with inline reduce of the it=9 tuple)
__global__ __launch_bounds__(256) void k_zfin(float2* __restrict__ z,
                                              const float2* __restrict__ p9,
                                              const float* __restrict__ scal,
                                              const float* __restrict__ part){
  __shared__ float red5[4][5];
  int tid = threadIdx.x, g = tid >> 6, j = tid & 63;
  float v[5];
  #pragma unroll
  for (int q = 0; q < 5; q++){
    float x = part[q*1024+tid] + part[q*1024+tid+256]
            + part[q*1024+tid+512] + part[q*1024+tid+768];
    for (int off = 32; off; off >>= 1) x += __shfl_down(x, off);
    v[q] = x;
  }
  if (j == 0){
    #pragma unroll
    for (int q = 0; q < 5; q++) red5[g][q] = v[q];
  }
  __syncthreads();
  float f0 = red5[0][0]+red5[1][0]+red5[2][0]+red5[3][0];
  float f1 = red5[0][1]+red5[1][1]+red5[2][1]+red5[3][1];
  float f2 = red5[0][2]+red5[1][2]+red5[2][2]+red5[3][2];
  float f3 = red5[0][3]+red5[1][3]+red5[2][3]+red5[3][3];
  float f4 = red5[0][4]+red5[1][4]+red5[2][4]+red5[3][4];
  float a_re, a_im, beta;
  cg_chain(scal, f0,f1,f2,f3,f4, scal[0], 10, a_re, a_im, beta);
  int idx = blockIdx.x*256 + tid;
  float2 pe = p9[idx], ze = z[idx];
  z[idx] = make_float2(ze.x + a_re*pe.x - a_im*pe.y,
                       ze.y + a_re*pe.y + a_im*pe.x);
}

extern "C" void kernel_launch(void* const* d_in, const int* in_sizes, int n_in,
                              void* d_out, int out_size, void* d_ws, size_t ws_size,
                              hipStream_t stream){
  const float2* y    = (const float2*)d_in[0];
  const float2* mo   = (const float2*)d_in[1];
  const float2* sens = (const float2*)d_in[2];
  const float2* Lt   = (const float2*)d_in[3];
  const float*  mask = (const float*)d_in[4];

  float* w = (float*)d_ws;
  float*  scal = w;                                  // 128 floats
  float*  part = w + 128;                            // 6*1024 floats (block partials)
  float*  W9   = w + 128 + 6144;                     // 9*HW floats
  float2* bufA = (float2*)(W9 + 9*HW);               // 30 planes (transposed k-space)
  float2* bufB = bufA + (size_t)30*HW;               // 30 planes (row-major)
  float2* p0   = bufB + (size_t)30*HW;
  float2* p1   = p0 + (size_t)3*HW;
  float2* r0   = p1 + (size_t)3*HW;
  float2* r1   = r0 + (size_t)3*HW;
  float2* Ap   = r1 + (size_t)3*HW;
  float2* z    = (float2*)d_out;

  // setup
  k_setup<<<2816, 256, 0, stream>>>(mask, Lt, y, W9, bufB, scal, part);
  k_rows_plain<<<dim3(32, 30), 512, 0, stream>>>(bufB, bufA);
  k_cols_plain<<<dim3(32, 30), 512, 0, stream>>>(bufA, bufB);
  k_compute_b<<<768, 256, 0, stream>>>(bufB, sens, mo, p0, r0, z, part);

  // CG iterations: 3 kernels each (scalar reduce fused into rows_op)
  for (int it = 0; it < 10; it++){
    float2* pprev = (it == 0) ? p0 : ((it & 1) ? p0 : p1);
    float2* rprev = (it == 0) ? r0 : ((it & 1) ? r0 : r1);
    float2* pw = (it & 1) ? p1 : p0;   // p_it
    float2* rw = (it & 1) ? r1 : r0;   // r_it
    k_rows_op<<<dim3(32, 30), 256, 0, stream>>>(rprev, pprev, Ap, pw, rw, z, sens, bufA, scal, part, it);
    k_cols_W<<<dim3(64, 10), 384, 0, stream>>>(bufA, bufB, W9);
    k_rows_acc<<<dim3(256, 3), 320, 0, stream>>>(bufB, sens, pw, rw, Ap, part);
  }
  k_zfin<<<768, 256, 0, stream>>>(z, p1, scal, part);
}